// Round 13
// baseline (120.852 us; speedup 1.0000x reference)
//
#include <hip/hip_runtime.h>
#include <stdint.h>

// MaskedMHSA: B=2 T=2048 E=768 H=12 DH=64
#define NROWS 4096      // B*T
#define EMB   768
#define NQKV  2304      // 3*E
#define TSEQ  2048
#define VTSTR 2080      // vt row stride
#define XSTR  800       // xb / aout row stride
#define WSTR  800       // weight row stride
#define PSTR  800       // proj row stride (bf16)
#define NHEAD 12
#define NBH   24        // B*H

typedef unsigned short u16;
typedef u16  ushort4v __attribute__((ext_vector_type(4)));
typedef u16  ushort8 __attribute__((ext_vector_type(8)));
typedef __bf16 bf16x8 __attribute__((ext_vector_type(8)));
typedef float f32x4 __attribute__((ext_vector_type(4)));

typedef const __attribute__((address_space(1))) void* gas_ptr;
typedef __attribute__((address_space(3))) void* las_ptr;

__device__ __forceinline__ u16 f2bf(float f) {
  union { float f; uint32_t u; } v; v.f = f;
  uint32_t u = v.u;
  return (u16)((u + 0x7fffu + ((u >> 16) & 1u)) >> 16);
}
__device__ __forceinline__ float bf2f(u16 u) {
  union { uint32_t u; float f; } v; v.u = ((uint32_t)u) << 16;
  return v.f;
}
__device__ __forceinline__ uint32_t cvtpk(float lo, float hi) {
  uint32_t r;
  asm("v_cvt_pk_bf16_f32 %0, %1, %2" : "=v"(r) : "v"(lo), "v"(hi));
  return r;
}

#define VMCNT0 asm volatile("s_waitcnt vmcnt(0)" ::: "memory")
#define LGKM0  asm volatile("s_waitcnt lgkmcnt(0)" ::: "memory")
#define SBAR   __builtin_amdgcn_s_barrier()
#define SCHED0 __builtin_amdgcn_sched_barrier(0)
#define MFMA(a, b, c) __builtin_amdgcn_mfma_f32_16x16x32_bf16((a), (b), (c), 0, 0, 0)

// ---------------- unified pack kernel ----------------
// Task table: 26 chunks per (y): qi=0..7, nch=min(qi+1,4), len=(4qi+4)/nch,
// sorted length-descending. direct only for qi==0.
__global__ __launch_bounds__(256) void k_pack(const float* __restrict__ x, u16* __restrict__ xb,
                                              const float* __restrict__ Wq, const float* __restrict__ Wk,
                                              const float* __restrict__ Wv, u16* __restrict__ wt,
                                              const float* __restrict__ Wo, u16* __restrict__ wot,
                                              uint32_t* __restrict__ cnt, uint32_t* __restrict__ tbl) {
  int bid = blockIdx.x, tid = threadIdx.x;
  if (bid == 0) {
    if (tid < 8) cnt[tid] = 0;
    if (tid >= 64 && tid < 90) {
      int p = tid - 64;            // 0..25
      int myqi = 0, myc = 0, k = 0;
      for (int qi = 0; qi < 8; ++qi) {
        int nch = (qi + 1 < 4) ? qi + 1 : 4;
        for (int c = 0; c < nch; ++c) { if (k == p) { myqi = qi; myc = c; } ++k; }
      }
      int mynch = (myqi + 1 < 4) ? myqi + 1 : 4;
      int mylen = (4 * myqi + 4) / mynch;
      int t0 = myc * mylen, t1 = t0 + mylen;
      int myid = myqi * 4 + myc;
      int rank = 0;
      for (int qi = 0; qi < 8; ++qi) {
        int nch = (qi + 1 < 4) ? qi + 1 : 4;
        int len = (4 * qi + 4) / nch;
        for (int c = 0; c < nch; ++c) {
          int id = qi * 4 + c;
          if (len > mylen || (len == mylen && id < myid)) ++rank;
        }
      }
      tbl[rank] = (uint32_t)myqi | ((uint32_t)t0 << 8) | ((uint32_t)t1 << 16)
                | ((uint32_t)myc << 24) | (myqi == 0 ? 0x80000000u : 0u);
    }
  }
  if (bid < 1536) {
    int i = bid * 2048 + tid * 8;
    int row = i / EMB, col = i - row * EMB;
    float4 a = *(const float4*)(x + i);
    float4 b = *(const float4*)(x + i + 4);
    uint4 o;
    o.x = cvtpk(a.x, a.y); o.y = cvtpk(a.z, a.w);
    o.z = cvtpk(b.x, b.y); o.w = cvtpk(b.z, b.w);
    *(uint4*)(xb + (size_t)row * XSTR + col) = o;
    return;
  }
  __shared__ u16 lds[64][68];
  if (bid < 1968) {
    int t = bid - 1536;
    int sel = t / 144, rest = t - sel * 144;
    int h = rest / 12, ec = rest - h * 12;
    const float* W = sel == 0 ? Wq : (sel == 1 ? Wk : Wv);
    const float* src = W + ((size_t)(h * EMB + ec * 64) * 64);
    int e = tid >> 2, d0 = (tid & 3) * 16;
#pragma unroll
    for (int j = 0; j < 4; ++j) {
      float4 v = *(const float4*)(src + (size_t)e * 64 + d0 + 4 * j);
      ushort4v pk;
      uint32_t w0 = cvtpk(v.x, v.y), w1 = cvtpk(v.z, v.w);
      pk[0] = (u16)(w0 & 0xffff); pk[1] = (u16)(w0 >> 16);
      pk[2] = (u16)(w1 & 0xffff); pk[3] = (u16)(w1 >> 16);
      *(ushort4v*)(&lds[e][d0 + 4 * j]) = pk;
    }
    __syncthreads();
    int d = tid >> 2, e0 = (tid & 3) * 16;
    ushort8 o0, o1;
#pragma unroll
    for (int j = 0; j < 8; ++j) { o0[j] = lds[e0 + j][d]; o1[j] = lds[e0 + 8 + j][d]; }
    int n = sel * EMB + h * 64 + d;
    u16* dst = wt + (size_t)n * WSTR + ec * 64 + e0;
    *(ushort8*)dst = o0;
    *(ushort8*)(dst + 8) = o1;
  } else {
    int t = bid - 1968;
    int er = t / 12, nc = t - er * 12;
    int e = tid >> 2, n0 = (tid & 3) * 16;
#pragma unroll
    for (int j = 0; j < 4; ++j) {
      float4 v = *(const float4*)(Wo + (size_t)(er * 64 + e) * EMB + nc * 64 + n0 + 4 * j);
      ushort4v pk;
      uint32_t w0 = cvtpk(v.x, v.y), w1 = cvtpk(v.z, v.w);
      pk[0] = (u16)(w0 & 0xffff); pk[1] = (u16)(w0 >> 16);
      pk[2] = (u16)(w1 & 0xffff); pk[3] = (u16)(w1 >> 16);
      *(ushort4v*)(&lds[e][n0 + 4 * j]) = pk;
    }
    __syncthreads();
    int n = tid >> 2, e0 = (tid & 3) * 16;
    ushort8 o0, o1;
#pragma unroll
    for (int j = 0; j < 8; ++j) { o0[j] = lds[e0 + j][n]; o1[j] = lds[e0 + 8 + j][n]; }
    u16* dst = wot + (size_t)(nc * 64 + n) * WSTR + er * 64 + e0;
    *(ushort8*)dst = o0;
    *(ushort8*)(dst + 8) = o1;
  }
}

// ---------------- GEMM: C[M,N] = A[M,K] * Bt[N,K]^T + bias ----------------
// OUT_MODE 1: bf16 out (stride PSTR), bias b0.
// OUT_MODE 2: QKV -> per-head packed q/k + transposed v.
template<int BM, int BN, int OUT_MODE>
__global__ __launch_bounds__(256) void k_gemm(const u16* __restrict__ A, const u16* __restrict__ Bt,
                                              const float* __restrict__ b0, const float* __restrict__ b1,
                                              const float* __restrict__ b2, void* __restrict__ Cout,
                                              u16* __restrict__ qpk, u16* __restrict__ kpk,
                                              u16* __restrict__ vtout,
                                              int M, int N, int K, int lda, int ldb) {
  constexpr int MR = BM / 32, NR = BN / 32;
  __shared__ u16 lds_a[BM * 64];
  __shared__ u16 lds_b[BN * 64];
  int tid = threadIdx.x;
  int w = tid >> 6, lane = tid & 63;
  int wr = w >> 1, wc = w & 1;
  int m0 = blockIdx.x * BM, n0 = blockIdx.y * BN;
  int lrow = lane & 15, g = lane >> 4;

  f32x4 zero = {0.f, 0.f, 0.f, 0.f};
  f32x4 acc[MR][NR];
  for (int m = 0; m < MR; ++m) for (int n = 0; n < NR; ++n) acc[m][n] = zero;

  int l8 = lane >> 3, c8 = lane & 7;

  for (int k0 = 0; k0 < K; k0 += 64) {
#pragma unroll
    for (int i = 0; i < BM / 32; ++i) {
      int row = w * (BM / 4) + 8 * i + l8;
      int c16 = c8 ^ (row & 7);
      const u16* ga = A + (size_t)(m0 + row) * lda + k0 + c16 * 8;
      __builtin_amdgcn_global_load_lds((gas_ptr)ga, (las_ptr)(lds_a + (w * (BM / 4) + 8 * i) * 64), 16, 0, 0);
    }
#pragma unroll
    for (int i = 0; i < BN / 32; ++i) {
      int row = w * (BN / 4) + 8 * i + l8;
      int c16 = c8 ^ (row & 7);
      const u16* gb = Bt + (size_t)(n0 + row) * ldb + k0 + c16 * 8;
      __builtin_amdgcn_global_load_lds((gas_ptr)gb, (las_ptr)(lds_b + (w * (BN / 4) + 8 * i) * 64), 16, 0, 0);
    }
    __syncthreads();
    bf16x8 af[MR][2], bfr[NR][2];
#pragma unroll
    for (int m = 0; m < MR; ++m)
#pragma unroll
      for (int kc = 0; kc < 2; ++kc) {
        int row = wr * (BM / 2) + m * 16 + lrow;
        int ch = (kc * 4 + g) ^ (row & 7);
        af[m][kc] = *(const bf16x8*)(lds_a + row * 64 + ch * 8);
      }
#pragma unroll
    for (int n = 0; n < NR; ++n)
#pragma unroll
      for (int kc = 0; kc < 2; ++kc) {
        int row = wc * (BN / 2) + n * 16 + lrow;
        int ch = (kc * 4 + g) ^ (row & 7);
        bfr[n][kc] = *(const bf16x8*)(lds_b + row * 64 + ch * 8);
      }
#pragma unroll
    for (int kc = 0; kc < 2; ++kc)
#pragma unroll
      for (int m = 0; m < MR; ++m)
#pragma unroll
        for (int n = 0; n < NR; ++n)
          acc[m][n] = MFMA(af[m][kc], bfr[n][kc], acc[m][n]);
    __syncthreads();
  }

#pragma unroll
  for (int m = 0; m < MR; ++m)
#pragma unroll
    for (int n = 0; n < NR; ++n) {
      int col = n0 + wc * (BN / 2) + n * 16 + lrow;
      float bcol;
      if (OUT_MODE == 1) bcol = b0[col];
      else {
        int sel = col >= 1536 ? 2 : (col >= 768 ? 1 : 0);
        const float* bs = sel == 0 ? b0 : (sel == 1 ? b1 : b2);
        bcol = bs[col - sel * EMB];
      }
      int row0 = m0 + wr * (BM / 2) + m * 16 + 4 * g;
      if (OUT_MODE == 2) {
        int sel = col >= 1536 ? 2 : (col >= 768 ? 1 : 0);
        int c = col - sel * EMB;
        int hh = c >> 6, d = c & 63;
        int bb = row0 >> 11, t = row0 & 2047;
        int y = bb * NHEAD + hh;
        if (sel == 2) {
          ushort4v pk;
#pragma unroll
          for (int r = 0; r < 4; ++r) pk[r] = f2bf(acc[m][n][r] + bcol);
          *(ushort4v*)(vtout + (size_t)(y * 64 + d) * VTSTR + t) = pk;
        } else {
          u16* dst = (sel == 0 ? qpk : kpk) + (size_t)(y * TSEQ + t) * 64 + d;
#pragma unroll
          for (int r = 0; r < 4; ++r) dst[r * 64] = f2bf(acc[m][n][r] + bcol);
        }
      } else {
#pragma unroll
        for (int r = 0; r < 4; ++r) {
          int row = row0 + r;
          ((u16*)Cout)[(size_t)row * PSTR + col] = f2bf(acc[m][n][r] + bcol);
        }
      }
    }
}

// ---------------- causal flash attention: 8 waves x 32 q-rows ----------------
#define QKROW(SB) do { \
    bf16x8 ka0 = *(const bf16x8*)(kb + ((((SB) * 16 + ql) * 64 + 8 * g) ^ swz)); \
    bf16x8 ka1 = *(const bf16x8*)(kb + ((((SB) * 16 + ql) * 64 + 32 + 8 * g) ^ swz)); \
    st##SB##q0 = MFMA(ka0, bq00, st##SB##q0); st##SB##q0 = MFMA(ka1, bq01, st##SB##q0); \
    st##SB##q1 = MFMA(ka0, bq10, st##SB##q1); st##SB##q1 = MFMA(ka1, bq11, st##SB##q1); \
  } while (0)

#define SMX1(STV, SB, QC, LR) do { \
    float _v0 = __builtin_fmaf(STV[0], sc2, -2.0f); \
    float _v1 = __builtin_fmaf(STV[1], sc2, -2.0f); \
    float _v2 = __builtin_fmaf(STV[2], sc2, -2.0f); \
    float _v3 = __builtin_fmaf(STV[3], sc2, -2.0f); \
    if (maskt) { \
      int _sg = s0 + (SB) * 16 + 4 * g; \
      int _qq = qw0 + (QC) * 16 + ql; \
      if (_sg + 0 > _qq) _v0 = -1e30f; \
      if (_sg + 1 > _qq) _v1 = -1e30f; \
      if (_sg + 2 > _qq) _v2 = -1e30f; \
      if (_sg + 3 > _qq) _v3 = -1e30f; \
    } \
    float _e0 = __builtin_amdgcn_exp2f(_v0), _e1 = __builtin_amdgcn_exp2f(_v1); \
    float _e2 = __builtin_amdgcn_exp2f(_v2), _e3 = __builtin_amdgcn_exp2f(_v3); \
    LR += (_e0 + _e1) + (_e2 + _e3); \
    uint2 _dw; _dw.x = cvtpk(_e0, _e1); _dw.y = cvtpk(_e2, _e3); \
    *(uint2*)(pw + ((((QC) * 16 + ql) * 64 + (SB) * 16 + 4 * g) ^ swz)) = _dw; \
  } while (0)

#define PVROW(DB) do { \
    bf16x8 vb0 = *(const bf16x8*)(vb + ((((DB) * 16 + ql) * 64 + 8 * g) ^ swz)); \
    bf16x8 vb1 = *(const bf16x8*)(vb + ((((DB) * 16 + ql) * 64 + 32 + 8 * g) ^ swz)); \
    o##DB##q0 = MFMA(ap00, vb0, o##DB##q0); o##DB##q0 = MFMA(ap01, vb1, o##DB##q0); \
    o##DB##q1 = MFMA(ap10, vb0, o##DB##q1); o##DB##q1 = MFMA(ap11, vb1, o##DB##q1); \
  } while (0)

#define OUTD(DB, QC, PTR, STRIDE, L0, L1, L2, L3) do { \
    (PTR)[0 * (STRIDE) + (DB) * 16] = f2bf(o##DB##q##QC[0] * (L0)); \
    (PTR)[1 * (STRIDE) + (DB) * 16] = f2bf(o##DB##q##QC[1] * (L1)); \
    (PTR)[2 * (STRIDE) + (DB) * 16] = f2bf(o##DB##q##QC[2] * (L2)); \
    (PTR)[3 * (STRIDE) + (DB) * 16] = f2bf(o##DB##q##QC[3] * (L3)); \
  } while (0)

__global__ __launch_bounds__(512, 2) void k_attn(const u16* __restrict__ qpk, const u16* __restrict__ kpk,
                                                 const u16* __restrict__ vt,
                                                 u16* __restrict__ aout, uint32_t* __restrict__ cnt,
                                                 const uint32_t* __restrict__ tbl,
                                                 u16* __restrict__ pO, float* __restrict__ pL) {
  __shared__ u16 kbuf[2][64 * 64];   // 16 KB
  __shared__ u16 vbuf[2][64 * 64];   // 16 KB
  __shared__ u16 pbuf[8][32 * 64];   // 32 KB -> 64 KB total
  int tid = threadIdx.x;
  int w = tid >> 6, lane = tid & 63;
  int ql = lane & 15, g = lane >> 4;
  int xcd = blockIdx.x & 7;
  const float sc2 = 0.18033688f;  // (1/8) * log2(e)
  u16* pw = &pbuf[w][0];
  int swz = (ql & 7) << 3;
  int srow = tid >> 3, sc8 = tid & 7;
  volatile int* taskp = (volatile int*)&pbuf[0][0];
  f32x4 zero = {0.f, 0.f, 0.f, 0.f};

  for (;;) {
    if (tid == 0) *taskp = (int)atomicAdd(&cnt[xcd], 1u);
    __syncthreads();
    int tau = *taskp;
    __syncthreads();
    if (tau >= 78) break;

    int rank = tau / 3, yl = tau - rank * 3;
    uint32_t te = tbl[rank];
    int qi = te & 0xff, t0 = (te >> 8) & 0xff, t1ex = (te >> 16) & 0xff, cslot = (te >> 24) & 0x7f;
    bool direct = (te >> 31) != 0;

    int y = xcd * 3 + yl;
    int b = y / NHEAD, h = y - b * NHEAD;
    int qb0 = qi * 256, qw0 = qb0 + w * 32;
    int qtw = qw0 >> 6;               // mask needed for tiles >= qtw

    const u16* qp0 = qpk + (size_t)(y * TSEQ + qw0 + ql) * 64;
    const u16* qp1 = qpk + (size_t)(y * TSEQ + qw0 + 16 + ql) * 64;
    bf16x8 bq00 = *(const bf16x8*)(qp0 + 8 * g);
    bf16x8 bq01 = *(const bf16x8*)(qp0 + 32 + 8 * g);
    bf16x8 bq10 = *(const bf16x8*)(qp1 + 8 * g);
    bf16x8 bq11 = *(const bf16x8*)(qp1 + 32 + 8 * g);

    const u16* kst = kpk + (size_t)y * TSEQ * 64;
    const u16* vst = vt + (size_t)y * 64 * VTSTR;

    f32x4 o0q0 = zero, o1q0 = zero, o2q0 = zero, o3q0 = zero;
    f32x4 o0q1 = zero, o1q1 = zero, o2q1 = zero, o3q1 = zero;
    float lr0 = 0.f, lr1 = 0.f;

    auto STAGE = [&](int bi, int t_) {
      int c16 = sc8 ^ (srow & 7);
      const u16* gk = kst + (size_t)t_ * 4096 + srow * 64 + c16 * 8;
      __builtin_amdgcn_global_load_lds((gas_ptr)gk, (las_ptr)(&kbuf[bi][(8 * w) * 64]), 16, 0, 0);
      const u16* gv = vst + (size_t)srow * VTSTR + t_ * 64 + c16 * 8;
      __builtin_amdgcn_global_load_lds((gas_ptr)gv, (las_ptr)(&vbuf[bi][(8 * w) * 64]), 16, 0, 0);
    };

    STAGE(t0 & 1, t0);
    for (int t = t0; t < t1ex; ++t) {
      int cur = t & 1;
      VMCNT0;
      SBAR;
      if (t + 1 < t1ex) STAGE(cur ^ 1, t + 1);

      const u16* kb = &kbuf[cur][0];
      const u16* vb = &vbuf[cur][0];
      int s0 = t * 64;
      bool maskt = (t >= qtw);

      f32x4 st0q0 = zero, st1q0 = zero, st2q0 = zero, st3q0 = zero;
      f32x4 st0q1 = zero, st1q1 = zero, st2q1 = zero, st3q1 = zero;
      __builtin_amdgcn_s_setprio(1);
      QKROW(0); QKROW(1); QKROW(2); QKROW(3);
      __builtin_amdgcn_s_setprio(0);

      SMX1(st0q0, 0, 0, lr0); SMX1(st1q0, 1, 0, lr0); SMX1(st2q0, 2, 0, lr0); SMX1(st3q0, 3, 0, lr0);
      SMX1(st0q1, 0, 1, lr1); SMX1(st1q1, 1, 1, lr1); SMX1(st2q1, 2, 1, lr1); SMX1(st3q1, 3, 1, lr1);

      LGKM0; SCHED0;
      bf16x8 ap00 = *(const bf16x8*)(pw + (((0 * 16 + ql) * 64 + 8 * g) ^ swz));
      bf16x8 ap01 = *(const bf16x8*)(pw + (((0 * 16 + ql) * 64 + 32 + 8 * g) ^ swz));
      bf16x8 ap10 = *(const bf16x8*)(pw + (((1 * 16 + ql) * 64 + 8 * g) ^ swz));
      bf16x8 ap11 = *(const bf16x8*)(pw + (((1 * 16 + ql) * 64 + 32 + 8 * g) ^ swz));

      __builtin_amdgcn_s_setprio(1);
      PVROW(0); PVROW(1); PVROW(2); PVROW(3);
      __builtin_amdgcn_s_setprio(0);
    }

    float lw0 = lr0, lw1 = lr1;
    lw0 += __shfl_xor(lw0, 16); lw0 += __shfl_xor(lw0, 32);
    lw1 += __shfl_xor(lw1, 16); lw1 += __shfl_xor(lw1, 32);

    if (direct) {
      float li0 = 1.0f / lw0, li1 = 1.0f / lw1;
      float a0 = __shfl(li0, 4 * g + 0), a1 = __shfl(li0, 4 * g + 1);
      float a2 = __shfl(li0, 4 * g + 2), a3 = __shfl(li0, 4 * g + 3);
      u16* ab0 = aout + (size_t)(b * TSEQ + qw0 + 4 * g) * XSTR + h * 64 + ql;
      OUTD(0, 0, ab0, XSTR, a0, a1, a2, a3); OUTD(1, 0, ab0, XSTR, a0, a1, a2, a3);
      OUTD(2, 0, ab0, XSTR, a0, a1, a2, a3); OUTD(3, 0, ab0, XSTR, a0, a1, a2, a3);
      float c0 = __shfl(li1, 4 * g + 0), c1 = __shfl(li1, 4 * g + 1);
      float c2 = __shfl(li1, 4 * g + 2), c3 = __shfl(li1, 4 * g + 3);
      u16* ab1 = aout + (size_t)(b * TSEQ + qw0 + 16 + 4 * g) * XSTR + h * 64 + ql;
      OUTD(0, 1, ab1, XSTR, c0, c1, c2, c3); OUTD(1, 1, ab1, XSTR, c0, c1, c2, c3);
      OUTD(2, 1, ab1, XSTR, c0, c1, c2, c3); OUTD(3, 1, ab1, XSTR, c0, c1, c2, c3);
    } else {
      int blk2 = (y * 8 + qi) * 4 + cslot;
      u16* po = pO + (size_t)blk2 * 16384;
      float* pl = pL + (size_t)blk2 * 256;
      if (g == 0) { pl[w * 32 + ql] = lw0; pl[w * 32 + 16 + ql] = lw1; }
      u16* pb0 = po + (w * 32 + 4 * g) * 64 + ql;
      OUTD(0, 0, pb0, 64, 1.f, 1.f, 1.f, 1.f); OUTD(1, 0, pb0, 64, 1.f, 1.f, 1.f, 1.f);
      OUTD(2, 0, pb0, 64, 1.f, 1.f, 1.f, 1.f); OUTD(3, 0, pb0, 64, 1.f, 1.f, 1.f, 1.f);
      u16* pb1 = po + (w * 32 + 16 + 4 * g) * 64 + ql;
      OUTD(0, 1, pb1, 64, 1.f, 1.f, 1.f, 1.f); OUTD(1, 1, pb1, 64, 1.f, 1.f, 1.f, 1.f);
      OUTD(2, 1, pb1, 64, 1.f, 1.f, 1.f, 1.f); OUTD(3, 1, pb1, 64, 1.f, 1.f, 1.f, 1.f);
    }
  }
}

// ---------------- combine split-K partials ----------------
// grid 768: blk -> (y, qi, quarter). nch = min(qi+1,4); qi==0 is direct (skip).
__global__ __launch_bounds__(256) void k_combine(const u16* __restrict__ pO, const float* __restrict__ pL,
                                                 u16* __restrict__ aout) {
  int blk = blockIdx.x;
  int u = blk >> 2, quarter = blk & 3;
  int y = u >> 3, qi = u & 7;
  int nch = (qi + 1 < 4) ? qi + 1 : 4;
  if (nch < 2) return;
  int b = y / NHEAD, h = y - b * NHEAD;
  int tid = threadIdx.x;
  int rl = quarter * 64 + (tid >> 2), c0 = (tid & 3) * 16;
  float l = 0.f;
#pragma unroll 4
  for (int c = 0; c < 4; ++c)
    if (c < nch) l += pL[((size_t)u * 4 + c) * 256 + rl];
  float rinv = 1.0f / l;
  float acc[16];
#pragma unroll
  for (int j = 0; j < 16; ++j) acc[j] = 0.f;
#pragma unroll 4
  for (int c = 0; c < 4; ++c)
    if (c < nch) {
      const u16* p = pO + ((size_t)u * 4 + c) * 16384 + rl * 64 + c0;
      ushort8 a0 = *(const ushort8*)p;
      ushort8 a1 = *(const ushort8*)(p + 8);
#pragma unroll
      for (int j = 0; j < 8; ++j) { acc[j] += bf2f(a0[j]); acc[8 + j] += bf2f(a1[j]); }
    }
  ushort8 o0, o1;
#pragma unroll
  for (int j = 0; j < 8; j += 2) {
    uint32_t w0 = cvtpk(acc[j] * rinv, acc[j + 1] * rinv);
    o0[j] = (u16)(w0 & 0xffff); o0[j + 1] = (u16)(w0 >> 16);
    uint32_t w1 = cvtpk(acc[8 + j] * rinv, acc[9 + j] * rinv);
    o1[j] = (u16)(w1 & 0xffff); o1[j + 1] = (u16)(w1 >> 16);
  }
  u16* dst = aout + (size_t)(b * TSEQ + qi * 256 + rl) * XSTR + h * 64 + c0;
  *(ushort8*)dst = o0;
  *(ushort8*)(dst + 8) = o1;
}

// ---------------- LayerNorm + residual (bf16 proj, wave-per-row vectorized) ----------------
__global__ __launch_bounds__(256) void k_ln_res(const u16* __restrict__ proj, const float* __restrict__ x,
                                                const float* __restrict__ gamma, const float* __restrict__ beta,
                                                float* __restrict__ out) {
  int w = threadIdx.x >> 6, lane = threadIdx.x & 63;
  int row = blockIdx.x * 4 + w;
  const u16* pr = proj + (size_t)row * PSTR;
  const float* xr = x + (size_t)row * EMB;
  float* orow = out + (size_t)row * EMB;
  int c0 = 12 * lane;
  ushort4v p0 = *(const ushort4v*)(pr + c0);
  ushort4v p1 = *(const ushort4v*)(pr + c0 + 4);
  ushort4v p2 = *(const ushort4v*)(pr + c0 + 8);
  float v[12];
#pragma unroll
  for (int j = 0; j < 4; ++j) { v[j] = bf2f(p0[j]); v[4 + j] = bf2f(p1[j]); v[8 + j] = bf2f(p2[j]); }
  float s = 0.f, s2 = 0.f;
#pragma unroll
  for (int j = 0; j < 12; ++j) { s += v[j]; s2 += v[j] * v[j]; }
#pragma unroll
  for (int m = 1; m < 64; m <<= 1) { s += __shfl_xor(s, m); s2 += __shfl_xor(s2, m); }
  float mu = s * (1.f / EMB);
  float var = s2 * (1.f / EMB) - mu * mu;
  float rstd = rsqrtf(var + 1e-5f);
  float4 xv0 = *(const float4*)(xr + c0);
  float4 xv1 = *(const float4*)(xr + c0 + 4);
  float4 xv2 = *(const float4*)(xr + c0 + 8);
  float4 g0 = *(const float4*)(gamma + c0);
  float4 g1 = *(const float4*)(gamma + c0 + 4);
  float4 g2 = *(const float4*)(gamma + c0 + 8);
  float4 b0 = *(const float4*)(beta + c0);
  float4 b1 = *(const float4*)(beta + c0 + 4);
  float4 b2 = *(const float4*)(beta + c0 + 8);
  float4 o0, o1, o2;
#pragma unroll
  for (int j = 0; j < 4; ++j) {
    o0[j] = xv0[j] + (v[j]     - mu) * rstd * g0[j] + b0[j];
    o1[j] = xv1[j] + (v[4 + j] - mu) * rstd * g1[j] + b1[j];
    o2[j] = xv2[j] + (v[8 + j] - mu) * rstd * g2[j] + b2[j];
  }
  *(float4*)(orow + c0) = o0;
  *(float4*)(orow + c0 + 4) = o1;
  *(float4*)(orow + c0 + 8) = o2;
}

// ---------------- launch ----------------
extern "C" void kernel_launch(void* const* d_in, const int* in_sizes, int n_in,
                              void* d_out, int out_size, void* d_ws, size_t ws_size,
                              hipStream_t stream) {
  const float* x     = (const float*)d_in[0];
  const float* Wq    = (const float*)d_in[1];
  const float* bq    = (const float*)d_in[2];
  const float* Wk    = (const float*)d_in[3];
  const float* bk    = (const float*)d_in[4];
  const float* Wv    = (const float*)d_in[5];
  const float* bv    = (const float*)d_in[6];
  const float* Wo    = (const float*)d_in[7];
  const float* bo    = (const float*)d_in[8];
  const float* gamma = (const float*)d_in[9];
  const float* beta  = (const float*)d_in[10];
  float* out = (float*)d_out;

  char* ws = (char*)d_ws;
  size_t off = 0;
  u16* xb    = (u16*)(ws + off); off += (size_t)NROWS * XSTR * 2;
  u16* wqkvt = (u16*)(ws + off); off += (size_t)NQKV * WSTR * 2;
  u16* wot   = (u16*)(ws + off); off += (size_t)EMB * WSTR * 2;
  uint32_t* cnt = (uint32_t*)(ws + off); off += 64;
  uint32_t* tbl = (uint32_t*)(ws + off); off += 512;
  u16* qpk   = (u16*)(ws + off); off += (size_t)NBH * TSEQ * 64 * 2;
  u16* kpk   = (u16*)(ws + off); off += (size_t)NBH * TSEQ * 64 * 2;
  u16* vt    = (u16*)(ws + off); off += (size_t)NBH * 64 * VTSTR * 2;
  u16* aout  = (u16*)(ws + off); off += (size_t)NROWS * XSTR * 2;
  u16* pO    = (u16*)(ws + off); off += (size_t)NBH * 8 * 4 * 16384 * 2;  // 25.2 MB
  float* pL  = (float*)(ws + off); off += (size_t)NBH * 8 * 4 * 256 * 4;  // 786 KB
  u16* proj = qpk;  // alias qpk (bf16 proj, 1.28 MB < qpk), dead after attention

  k_pack<<<dim3(2112), 256, 0, stream>>>(x, xb, Wq, Wk, Wv, wqkvt, Wo, wot, cnt, tbl);
  k_gemm<128, 128, 2><<<dim3(NROWS / 128, NQKV / 128), 256, 0, stream>>>(
      xb, wqkvt, bq, bk, bv, nullptr, qpk, kpk, vt, NROWS, NQKV, EMB, XSTR, WSTR);
  k_attn<<<dim3(512), 512, 0, stream>>>(qpk, kpk, vt, aout, cnt, tbl, pO, pL);
  k_combine<<<dim3(768), 256, 0, stream>>>(pO, pL, aout);
  k_gemm<128, 64, 1><<<dim3(NROWS / 128, EMB / 64), 256, 0, stream>>>(
      aout, wot, bo, nullptr, nullptr, proj, nullptr, nullptr, nullptr, NROWS, EMB, EMB, XSTR, WSTR);
  k_ln_res<<<NROWS / 4, 256, 0, stream>>>(proj, x, gamma, beta, out);
}